// Round 6
// baseline (183.215 us; speedup 1.0000x reference)
//
#include <hip/hip_runtime.h>
#include <hip/hip_bf16.h>
#include <cmath>

#define BATCH 4
#define SEQ 2048
#define DM 1024
#define NS 16
#define M_ROWS (BATCH * SEQ)

typedef short bf16x8 __attribute__((ext_vector_type(8)));
typedef short bf16x4 __attribute__((ext_vector_type(4)));
typedef float f32x4 __attribute__((ext_vector_type(4)));

// fp32 -> bf16 round-to-nearest-even
__device__ __forceinline__ short f2bf(float f) {
    union { float f; unsigned u; } a; a.f = f;
    unsigned u = a.u;
    return (short)((u + 0x7fffu + ((u >> 16) & 1u)) >> 16);
}
__device__ __forceinline__ float bf2f(unsigned short s) {
    union { unsigned u; float f; } a; a.u = ((unsigned)s) << 16;
    return a.f;
}

#define LDS_CAST(p) ((__attribute__((address_space(3))) unsigned*)(p))
#define GLB_CAST(p) ((const __attribute__((address_space(1))) unsigned*)(p))

// ---------------------------------------------------------------------------
// Kernel 0: convert x, W1, W2, W3 fp32 -> bf16. Block-uniform segment select.
// Wcb = [W2(16 rows); W3(16 rows)], row-major, K contiguous.
// ---------------------------------------------------------------------------
__global__ void __launch_bounds__(256) convert_all(
    const float* __restrict__ x,  const float* __restrict__ W1,
    const float* __restrict__ W2, const float* __restrict__ W3,
    short* __restrict__ xb, short* __restrict__ W1b, short* __restrict__ Wcb)
{
    const int b = blockIdx.x;
    const int t = threadIdx.x;
    const float4* src; bf16x4* dst; int qbase;
    if (b < 2048)      { src = (const float4*)x;  dst = (bf16x4*)xb;  qbase = b * 1024; }
    else if (b < 2304) { src = (const float4*)W1; dst = (bf16x4*)W1b; qbase = (b - 2048) * 1024; }
    else if (b < 2308) { src = (const float4*)W2; dst = (bf16x4*)Wcb; qbase = (b - 2304) * 1024; }
    else               { src = (const float4*)W3; dst = (bf16x4*)(Wcb + NS * DM); qbase = (b - 2308) * 1024; }
    #pragma unroll
    for (int i = 0; i < 4; i++) {
        int q = qbase + i * 256 + t;
        float4 v = src[q];
        bf16x4 s;
        s.x = f2bf(v.x); s.y = f2bf(v.y); s.z = f2bf(v.z); s.w = f2bf(v.w);
        dst[q] = s;
    }
}

// ---------------------------------------------------------------------------
// Kernel 1: fused  z = xb @ W1b^T.  ROUND 6: concurrency push.
// R5 (4 blocks/CU) proved the latency/concurrency theory: occupancy 22->43%
// gave -16%.  This round: tile 64x64, grid (16 n, 128 m) = 2048 blocks, Wc
// staged NOT in LDS but read global->VGPR per fragment (64KB, hot in every
// L1/L2 -- the verified R4 path), LDS = 16.25KB, __launch_bounds__(256,6)
// -> target 6 blocks/CU = 24 waves = ~75% occupancy (1.75x R5).
// XCD mapping = R5 winner: grid.x = n-block -> per-XCD W1b slice (2 n-blocks
// = 256KB) L2-resident; xb streams via L3.  K-loop structure = R5's
// measured-best 2-barrier loop; fragment swizzle identical (0 conflicts).
// Waves split N 4-ways (acc[4][1]); bc via wave-uniform af[w] (verified).
// ---------------------------------------------------------------------------
__global__ void __launch_bounds__(256, 6) gemm_fused(
    const short* __restrict__ xb, const short* __restrict__ W1b,
    const short* __restrict__ Wcb, const float* __restrict__ b1,
    const float* __restrict__ b2,  const float* __restrict__ b3,
    float* __restrict__ out)
{
    __shared__ short As[64][64];     // 8 KB  x tile   [m][k]
    __shared__ short Bs[64][64];     // 8 KB  W1 tile  [n][k]
    __shared__ float bcs[64];

    const int n0 = blockIdx.x * 64;     // grid.x = 16 n-blocks -> XCD = x%8
    const int m0 = blockIdx.y * 64;     // grid.y = 128 m-blocks
    const int t = threadIdx.x;
    const int lane = t & 63;
    const int w = t >> 6;               // 0..3
    const int wn = w * 16;              // wave's n-slice (16 cols)
    const int lm = lane & 15;
    const int quad = lane >> 4;

    // staging: 8 chunks of 16B per 64-element row; 32-row groups
    const int sr  = t >> 3;               // 0..31
    const int sc  = t & 7;                // 0..7
    const int gch = (sc ^ (sr & 7)) * 8;  // swizzled k-element offset

    // loop-invariant staging pointers
    const short* pa = xb  + (size_t)(m0 + sr) * DM + gch;
    const short* pb = W1b + (size_t)(n0 + sr) * DM + gch;
    // Wc fragment pointers: direct global reads (64KB region, L1/L2-hot)
    const short* pW0 = Wcb + (size_t)(lm) * DM + quad * 8;        // W2 row lm
    const short* pW1 = Wcb + (size_t)(16 + lm) * DM + quad * 8;   // W3 row lm

    f32x4 acc[4] = {};   // main accumulators: [m-frag], n-frag = 1
    f32x4 abc[2] = {};   // bc partials for af[w]: h=0:W2 h=1:W3

    #pragma unroll
    for (int kk = 0; kk < 16; kk++) {
        const int ke = kk * 64;          // element offset, constant per iter
        // A: 64 rows in 2 groups of 32
        #pragma unroll
        for (int u = 0; u < 2; u++)
            __builtin_amdgcn_global_load_lds(GLB_CAST(pa + (size_t)(u * 32) * DM + ke),
                LDS_CAST(&As[u * 32 + sr][sc * 8]), 16, 0, 0);
        // B: 64 rows in 2 groups of 32
        #pragma unroll
        for (int u = 0; u < 2; u++)
            __builtin_amdgcn_global_load_lds(GLB_CAST(pb + (size_t)(u * 32) * DM + ke),
                LDS_CAST(&Bs[u * 32 + sr][sc * 8]), 16, 0, 0);
        __syncthreads();

        #pragma unroll
        for (int ks = 0; ks < 2; ks++) {
            // all fragment rows have (row&7) == (lm&7) -> shared chunk index
            const int cs = ((ks * 4 + quad) ^ (lm & 7)) * 8;
            const int eo = kk * 64 + ks * 32;   // Wc element offset
            bf16x8 af[4], bfv, wcv[2];
            #pragma unroll
            for (int i = 0; i < 4; i++)
                af[i] = *(const bf16x8*)&As[i * 16 + lm][cs];
            bfv = *(const bf16x8*)&Bs[wn + lm][cs];
            wcv[0] = *(const bf16x8*)(pW0 + eo);
            wcv[1] = *(const bf16x8*)(pW1 + eo);

            #pragma unroll
            for (int i = 0; i < 4; i++)
                acc[i] = __builtin_amdgcn_mfma_f32_16x16x32_bf16(
                    af[i], bfv, acc[i], 0, 0, 0);

            // bc: wave w accumulates for m-frag w. WAVE-UNIFORM branch,
            // CONSTANT indices (dynamic af[w] would demote to scratch).
            if (w == 0) {
                abc[0] = __builtin_amdgcn_mfma_f32_16x16x32_bf16(af[0], wcv[0], abc[0], 0, 0, 0);
                abc[1] = __builtin_amdgcn_mfma_f32_16x16x32_bf16(af[0], wcv[1], abc[1], 0, 0, 0);
            } else if (w == 1) {
                abc[0] = __builtin_amdgcn_mfma_f32_16x16x32_bf16(af[1], wcv[0], abc[0], 0, 0, 0);
                abc[1] = __builtin_amdgcn_mfma_f32_16x16x32_bf16(af[1], wcv[1], abc[1], 0, 0, 0);
            } else if (w == 2) {
                abc[0] = __builtin_amdgcn_mfma_f32_16x16x32_bf16(af[2], wcv[0], abc[0], 0, 0, 0);
                abc[1] = __builtin_amdgcn_mfma_f32_16x16x32_bf16(af[2], wcv[1], abc[1], 0, 0, 0);
            } else {
                abc[0] = __builtin_amdgcn_mfma_f32_16x16x32_bf16(af[3], wcv[0], abc[0], 0, 0, 0);
                abc[1] = __builtin_amdgcn_mfma_f32_16x16x32_bf16(af[3], wcv[1], abc[1], 0, 0, 0);
            }
        }
        __syncthreads();
    }

    // ---- bc reduce: lane holds rows w*16 + quad*4 + r, state col = lm ----
    float bb2 = b2[lm], bb3 = b3[lm];
    #pragma unroll
    for (int r = 0; r < 4; r++) {
        float p = (abc[0][r] + bb2) * (abc[1][r] + bb3);
        p += __shfl_xor(p, 1);
        p += __shfl_xor(p, 2);
        p += __shfl_xor(p, 4);
        p += __shfl_xor(p, 8);
        if (lm == 0) bcs[w * 16 + quad * 4 + r] = p;
    }
    __syncthreads();

    // ---- epilogue: D col(n)=lm, row(m)=quad*4+r; fast stable softplus ----
    const unsigned short* xbu = (const unsigned short*)xb;
    const float b1v = b1[n0 + wn + lm];

    #pragma unroll
    for (int i = 0; i < 4; i++) {
        #pragma unroll
        for (int r = 0; r < 4; r++) {
            int lrow = i * 16 + quad * 4 + r;
            int gm = m0 + lrow;
            float bcv = bcs[lrow];
            float z = acc[i][r] + b1v;
            float az = __builtin_fabsf(z);
            float sp = fmaxf(z, 0.f) + __logf(1.f + __expf(-az));
            size_t off = (size_t)gm * DM + n0 + wn + lm;
            out[off] = bf2f(xbu[off]) * sp * bcv;
        }
    }
}

extern "C" void kernel_launch(void* const* d_in, const int* in_sizes, int n_in,
                              void* d_out, int out_size, void* d_ws, size_t ws_size,
                              hipStream_t stream) {
    const float* x  = (const float*)d_in[0];
    const float* W1 = (const float*)d_in[1];
    const float* b1 = (const float*)d_in[2];
    const float* W2 = (const float*)d_in[3];
    const float* b2 = (const float*)d_in[4];
    const float* W3 = (const float*)d_in[5];
    const float* b3 = (const float*)d_in[6];
    // d_in[7] = A is dead math
    float* out = (float*)d_out;

    // ws: xb 16 MiB @0 | W1b 2 MiB @16M | Wcb 64 KiB @18M
    char* ws = (char*)d_ws;
    short* xb  = (short*)(ws);
    short* W1b = (short*)(ws + (size_t)16 * 1024 * 1024);
    short* Wcb = (short*)(ws + (size_t)18 * 1024 * 1024);

    convert_all<<<2312, 256, 0, stream>>>(x, W1, W2, W3, xb, W1b, Wcb);

    // grid (16 n-blocks, 128 m-blocks): linear%8 = n-block%8 = XCD ->
    // per-XCD W1b slice (2 n-blocks = 256KB) L2-resident, xb streams via L3.
    // 2048 blocks; residency target 6 blocks/CU (launch_bounds VGPR cap).
    dim3 grid(DM / 64, M_ROWS / 64);
    gemm_fused<<<grid, 256, 0, stream>>>(xb, W1b, Wcb, b1, b2, b3, out);
}